// Round 2
// baseline (2494.967 us; speedup 1.0000x reference)
//
#include <hip/hip_runtime.h>
#include <hip/hip_bf16.h>

#define H_    768
#define NH_   12
#define HD_   64
#define INTER_ 3072
#define NL_   6
#define NTOK  8192
#define SEG   512
#define NB    16
#define AW_   256
#define MIDW  5376   // 3H + INTER
#define CMB   3840   // H + INTER

typedef unsigned short u16;
typedef __bf16 bf16;
typedef bf16  bf16x8 __attribute__((ext_vector_type(8)));
typedef float f32x4  __attribute__((ext_vector_type(4)));
typedef u16   u16x8  __attribute__((ext_vector_type(8)));

#define GLOAD16(gp, lp) \
    __builtin_amdgcn_global_load_lds((const __attribute__((address_space(1))) void*)(gp), \
                                     (__attribute__((address_space(3))) void*)(lp), 16, 0, 0)

__device__ __forceinline__ u16 f2bf(float f) {
    union { float f; unsigned u; } v; v.f = f;
    unsigned u = v.u;
    u += 0x7fffu + ((u >> 16) & 1u);
    return (u16)(u >> 16);
}
__device__ __forceinline__ float bf2f(u16 h) {
    union { unsigned u; float f; } v; v.u = ((unsigned)h) << 16; return v.f;
}
__device__ __forceinline__ float gelu_f(float x) {
    float x3 = x * x * x;
    return 0.5f * x * (1.f + tanhf(0.7978845608028654f * (x + 0.044715f * x3)));
}

// ---------------- embed gather ----------------
__global__ void k_embed(const int* __restrict__ tokens, const float* __restrict__ embed,
                        float* __restrict__ x) {
    int row = blockIdx.x;
    int tok = tokens[row];
    const float* src = embed + (size_t)tok * H_;
    float* dst = x + (size_t)row * H_;
    for (int c = threadIdx.x; c < H_; c += blockDim.x) dst[c] = src[c];
}

// ---------------- rope tables (mimic jax fp32 path) ----------------
__global__ void k_tables(const float* __restrict__ ages, float* __restrict__ st,
                         float* __restrict__ ct) {
    int n = blockIdx.x * blockDim.x + threadIdx.x;
    if (n >= NTOK) return;
    float age = ages[n];
    for (int j = 0; j < 32; j++) {
        float e = (float)j * (2.0f / 31.0f);
        float invf = 1.0f / powf(10000.0f, e);
        float t = age * invf;
        st[n * 32 + j] = sinf(t);
        ct[n * 32 + j] = cosf(t);
    }
}

// ---------------- fp32 -> bf16 transpose (weights) ----------------
// src: [z][R][C] f32  ->  dst: [z][C][R] bf16
__global__ void k_transpose_bf16(const float* __restrict__ src, u16* __restrict__ dst,
                                 int R, int C) {
    __shared__ float T[64][65];
    int l = blockIdx.z;
    const float* s = src + (size_t)l * R * C;
    u16* d = dst + (size_t)l * R * C;
    int r0 = blockIdx.y * 64, c0 = blockIdx.x * 64;
    for (int i = threadIdx.x; i < 64 * 64; i += blockDim.x) {
        int r = i >> 6, c = i & 63;
        T[r][c] = s[(size_t)(r0 + r) * C + c0 + c];
    }
    __syncthreads();
    for (int i = threadIdx.x; i < 64 * 64; i += blockDim.x) {
        int rr = i >> 6, cc = i & 63;
        d[(size_t)(c0 + rr) * R + r0 + cc] = f2bf(T[cc][rr]);
    }
}

// ---------------- layernorm: wave per row ----------------
template<int FINAL>
__global__ __launch_bounds__(256) void k_ln(const float* __restrict__ x,
        const float* __restrict__ scale, const float* __restrict__ offset,
        float* __restrict__ xn_f, u16* __restrict__ xn_h, float* __restrict__ outf) {
    int wid = threadIdx.x >> 6, lane = threadIdx.x & 63;
    int row = blockIdx.x * 4 + wid;
    const float* xr = x + (size_t)row * H_;
    float4 v[3];
    float s = 0.f, sq = 0.f;
#pragma unroll
    for (int i = 0; i < 3; i++) {
        v[i] = *(const float4*)&xr[(i * 64 + lane) * 4];
        s  += v[i].x + v[i].y + v[i].z + v[i].w;
        sq += v[i].x * v[i].x + v[i].y * v[i].y + v[i].z * v[i].z + v[i].w * v[i].w;
    }
    for (int m = 1; m < 64; m <<= 1) { s += __shfl_xor(s, m); sq += __shfl_xor(sq, m); }
    float mean = s * (1.f / 768.f);
    float var  = sq * (1.f / 768.f) - mean * mean;
    float rstd = rsqrtf(fmaxf(var, 0.f) + 1e-5f);
#pragma unroll
    for (int i = 0; i < 3; i++) {
        int c0 = (i * 64 + lane) * 4;
        float4 sc = *(const float4*)&scale[c0];
        float4 of = *(const float4*)&offset[c0];
        float y0 = (v[i].x - mean) * rstd * sc.x + of.x;
        float y1 = (v[i].y - mean) * rstd * sc.y + of.y;
        float y2 = (v[i].z - mean) * rstd * sc.z + of.z;
        float y3 = (v[i].w - mean) * rstd * sc.w + of.w;
        if (FINAL) {
            *(float4*)&outf[(size_t)row * H_ + c0] = make_float4(y0, y1, y2, y3);
        } else {
            *(float4*)&xn_f[(size_t)row * H_ + c0] = make_float4(y0, y1, y2, y3);
            ushort4 h = make_ushort4(f2bf(y0), f2bf(y1), f2bf(y2), f2bf(y3));
            *(ushort4*)&xn_h[(size_t)row * H_ + c0] = h;
        }
    }
}

// ---------------- bf16 GEMM, 128xBN tile, BK=64, 4 waves, global_load_lds staging ----
// MODE 1 (BN=128): C(mid bf16) = A(xn_h [M][768]) * Bt(w_in_t [5376][768])^T + b_in; gelu col>=2304
// MODE 2 (BN=64):  X(f32)      = [attn | mid_ff] * Bt(w_out_t [768][3840])^T + b_out + xn_f
template<int MODE, int BN>
__global__ __launch_bounds__(256) void k_gemm(
        const u16* __restrict__ A, const u16* __restrict__ A2,
        const u16* __restrict__ Bt, const float* __restrict__ bias,
        const float* __restrict__ xn_f, u16* __restrict__ Cmid,
        float* __restrict__ Xout, int Ksz) {
    __shared__ __align__(16) u16 As[128 * 64];
    __shared__ __align__(16) u16 Bs[BN * 64];
    int m0 = blockIdx.x * 128;
    int n0 = blockIdx.y * BN;
    int tid = threadIdx.x;
    int wid = tid >> 6, lane = tid & 63;
    constexpr int MI = (BN == 128) ? 4 : 2;   // per-wave 16-row fragments
    constexpr int NI = 4;                      // per-wave 16-col fragments (64 cols)
    int wm = (BN == 128) ? (wid >> 1) : wid;
    int wn = (BN == 128) ? (wid & 1) : 0;
    f32x4 acc[MI][NI] = {};

    int r = tid >> 3;              // staging row within 32-row chunk
    int c = (tid & 7) * 8;         // staging col (u16)
    int wbase = (tid & 192) * 8;   // wave-uniform LDS chunk base (u16 elems): wid*512

    int nkt = Ksz / 64;
    for (int kt = 0; kt < nkt; kt++) {
        int k0 = kt * 64;
        const u16* Ap; int lda, acol;
        if (MODE == 2 && k0 >= H_) { Ap = A2; lda = MIDW; acol = 2304 + (k0 - H_); }
        else                       { Ap = A;  lda = H_;   acol = k0; }
#pragma unroll
        for (int i = 0; i < 4; i++)
            GLOAD16(&Ap[(size_t)(m0 + i * 32 + r) * lda + acol + c], &As[i * 2048 + wbase]);
#pragma unroll
        for (int i = 0; i < BN / 32; i++)
            GLOAD16(&Bt[(size_t)(n0 + i * 32 + r) * Ksz + k0 + c], &Bs[i * 2048 + wbase]);
        __syncthreads();
#pragma unroll
        for (int kk = 0; kk < 64; kk += 32) {
            bf16x8 af[MI], bfr[NI];
#pragma unroll
            for (int mi = 0; mi < MI; mi++)
                af[mi] = *(const bf16x8*)&As[(wm * (MI * 16) + mi * 16 + (lane & 15)) * 64 + kk + (lane >> 4) * 8];
#pragma unroll
            for (int ni = 0; ni < NI; ni++)
                bfr[ni] = *(const bf16x8*)&Bs[(wn * 64 + ni * 16 + (lane & 15)) * 64 + kk + (lane >> 4) * 8];
#pragma unroll
            for (int mi = 0; mi < MI; mi++)
#pragma unroll
                for (int ni = 0; ni < NI; ni++)
                    acc[mi][ni] = __builtin_amdgcn_mfma_f32_16x16x32_bf16(af[mi], bfr[ni], acc[mi][ni], 0, 0, 0);
        }
        __syncthreads();
    }
    // epilogue: D layout col=lane&15, row=(lane>>4)*4+reg
    int rbase = m0 + wm * (MI * 16), cbase = n0 + wn * 64;
#pragma unroll
    for (int mi = 0; mi < MI; mi++) {
#pragma unroll
        for (int ni = 0; ni < NI; ni++) {
            int col = cbase + ni * 16 + (lane & 15);
            float b = bias[col];
#pragma unroll
            for (int rr = 0; rr < 4; rr++) {
                int row = rbase + mi * 16 + (lane >> 4) * 4 + rr;
                float vv = acc[mi][ni][rr] + b;
                if (MODE == 1) {
                    if (col >= 2304) vv = gelu_f(vv);
                    Cmid[(size_t)row * MIDW + col] = f2bf(vv);
                } else {
                    Xout[(size_t)row * H_ + col] = vv + xn_f[(size_t)row * H_ + col];
                }
            }
        }
    }
}

// ---------------- rope on q,k (in place) + V transpose ----------------
__global__ __launch_bounds__(256) void k_rope_v(u16* __restrict__ mid,
        const float* __restrict__ st, const float* __restrict__ ct, u16* __restrict__ Vt) {
    int nb = blockIdx.x, h = blockIdx.y;
    int n0 = nb * 64;
    __shared__ u16 Vl[64][72];
    int tid = threadIdx.x;
    for (int i = tid; i < 64 * 32; i += 256) {
        int r = i >> 5, j = i & 31;
        int n = n0 + r;
        float s = st[n * 32 + j], c = ct[n * 32 + j];
        size_t base = (size_t)n * MIDW + h * 64 + 2 * j;
        float q0 = bf2f(mid[base]), q1 = bf2f(mid[base + 1]);
        mid[base]     = f2bf(q0 * c - q1 * s);
        mid[base + 1] = f2bf(q1 * c + q0 * s);
        float k0 = bf2f(mid[base + H_]), k1 = bf2f(mid[base + H_ + 1]);
        mid[base + H_]     = f2bf(k0 * c - k1 * s);
        mid[base + H_ + 1] = f2bf(k1 * c + k0 * s);
    }
    for (int i = tid; i < 64 * 64; i += 256) {
        int r = i >> 6, d = i & 63;
        Vl[r][d] = mid[(size_t)(n0 + r) * MIDW + 1536 + h * 64 + d];
    }
    __syncthreads();
    for (int i = tid; i < 64 * 64; i += 256) {
        int d = i >> 6, r = i & 63;
        Vt[(size_t)(h * 64 + d) * NTOK + n0 + r] = Vl[r][d];
    }
}

// ---------------- local windowed attention ----------------
// block: 128 threads (2 waves), 32 q-rows; grid: NH * NB * 16
__global__ __launch_bounds__(128) void k_attn(const u16* __restrict__ mid,
        const u16* __restrict__ Vt, u16* __restrict__ attn_out) {
    int bx = blockIdx.x;
    int h = bx >> 8, rem = bx & 255, b = rem >> 4, qq = rem & 15;
    int t0 = (qq * 32 - 255) >> 6; if (t0 < 0) t0 = 0;
    int tend = qq >> 1;
    int nt = tend - t0 + 1;          // <= 5
    int tid = threadIdx.x, wid = tid >> 6, lane = tid & 63;
    __shared__ float S[32][324];
    __shared__ float rl[32];
    int qrow0 = b * SEG + qq * 32;

    // Q fragments (rope already applied): wave's 16 rows
    bf16x8 qf[2];
    {
        int r = qrow0 + wid * 16 + (lane & 15);
        const u16* qp = &mid[(size_t)r * MIDW + h * 64];
        qf[0] = *(const bf16x8*)&qp[(lane >> 4) * 8];
        qf[1] = *(const bf16x8*)&qp[32 + (lane >> 4) * 8];
    }
    // S = Q K^T (scaled, masked)
    for (int t = 0; t < nt; t++) {
        int j0 = (t0 + t) * 64;
        f32x4 sa[4] = {};
#pragma unroll
        for (int kf = 0; kf < 2; kf++) {
            bf16x8 kfr[4];
#pragma unroll
            for (int nf = 0; nf < 4; nf++) {
                int key = b * SEG + j0 + nf * 16 + (lane & 15);
                kfr[nf] = *(const bf16x8*)&mid[(size_t)key * MIDW + H_ + h * 64 + kf * 32 + (lane >> 4) * 8];
            }
#pragma unroll
            for (int nf = 0; nf < 4; nf++)
                sa[nf] = __builtin_amdgcn_mfma_f32_16x16x32_bf16(qf[kf], kfr[nf], sa[nf], 0, 0, 0);
        }
#pragma unroll
        for (int nf = 0; nf < 4; nf++) {
            int j = j0 + nf * 16 + (lane & 15);
#pragma unroll
            for (int r = 0; r < 4; r++) {
                int row = wid * 16 + (lane >> 4) * 4 + r;
                int qi = qq * 32 + row;
                bool valid = (j <= qi) && (qi - j < AW_);
                S[row][t * 64 + nf * 16 + (lane & 15)] = valid ? sa[nf][r] * 0.125f : -1e30f;
            }
        }
    }
    __syncthreads();
    // softmax: 4 threads per row
    {
        int row = tid >> 2, sub = tid & 3;
        int ncol = nt * 64;
        float m = -1e30f;
        for (int c = sub; c < ncol; c += 4) m = fmaxf(m, S[row][c]);
        m = fmaxf(m, __shfl_xor(m, 1)); m = fmaxf(m, __shfl_xor(m, 2));
        float l = 0.f;
        for (int c = sub; c < ncol; c += 4) { float p = __expf(S[row][c] - m); S[row][c] = p; l += p; }
        l += __shfl_xor(l, 1); l += __shfl_xor(l, 2);
        if (sub == 0) rl[row] = 1.f / l;
    }
    __syncthreads();
    // O = P V
    f32x4 oacc[4] = {};
    for (int t = 0; t < nt; t++) {
#pragma unroll
        for (int kf = 0; kf < 2; kf++) {
            const float* sp = &S[wid * 16 + (lane & 15)][t * 64 + kf * 32 + (lane >> 4) * 8];
            float4 f1 = *(const float4*)sp;
            float4 f2 = *(const float4*)(sp + 4);
            u16x8 pt;
            pt[0] = f2bf(f1.x); pt[1] = f2bf(f1.y); pt[2] = f2bf(f1.z); pt[3] = f2bf(f1.w);
            pt[4] = f2bf(f2.x); pt[5] = f2bf(f2.y); pt[6] = f2bf(f2.z); pt[7] = f2bf(f2.w);
            bf16x8 pa = __builtin_bit_cast(bf16x8, pt);
#pragma unroll
            for (int nf = 0; nf < 4; nf++) {
                int d = h * 64 + nf * 16 + (lane & 15);
                const u16* vp = &Vt[(size_t)d * NTOK + b * SEG + (t0 + t) * 64 + kf * 32 + (lane >> 4) * 8];
                bf16x8 vb = *(const bf16x8*)vp;
                oacc[nf] = __builtin_amdgcn_mfma_f32_16x16x32_bf16(pa, vb, oacc[nf], 0, 0, 0);
            }
        }
    }
#pragma unroll
    for (int nf = 0; nf < 4; nf++) {
#pragma unroll
        for (int r = 0; r < 4; r++) {
            int row = wid * 16 + (lane >> 4) * 4 + r;
            float sc = rl[row];
            int grow = qrow0 + row;
            attn_out[(size_t)grow * H_ + h * 64 + nf * 16 + (lane & 15)] = f2bf(oacc[nf][r] * sc);
        }
    }
}

extern "C" void kernel_launch(void* const* d_in, const int* in_sizes, int n_in,
                              void* d_out, int out_size, void* d_ws, size_t ws_size,
                              hipStream_t stream) {
    const int*   tokens   = (const int*)d_in[0];
    const float* ages     = (const float*)d_in[1];
    const float* embed    = (const float*)d_in[4];
    const float* ln_scale = (const float*)d_in[5];
    const float* ln_off   = (const float*)d_in[6];
    const float* w_in     = (const float*)d_in[7];
    const float* b_in     = (const float*)d_in[8];
    const float* w_out    = (const float*)d_in[9];
    const float* b_out    = (const float*)d_in[10];
    const float* fscale   = (const float*)d_in[11];
    const float* foff     = (const float*)d_in[12];
    float* out = (float*)d_out;

    char* ws = (char*)d_ws;
    size_t off = 0;
    auto alloc = [&](size_t bytes) { void* p = ws + off; off += (bytes + 255) & ~(size_t)255; return p; };
    float* st      = (float*)alloc((size_t)NTOK * 32 * 4);
    float* ct      = (float*)alloc((size_t)NTOK * 32 * 4);
    float* x       = (float*)alloc((size_t)NTOK * H_ * 4);
    float* xn_f    = (float*)alloc((size_t)NTOK * H_ * 4);
    u16*   xn_h    = (u16*)alloc((size_t)NTOK * H_ * 2);
    u16*   mid     = (u16*)alloc((size_t)NTOK * MIDW * 2);
    u16*   Vt      = (u16*)alloc((size_t)H_ * NTOK * 2);
    u16*   attn    = (u16*)alloc((size_t)NTOK * H_ * 2);
    u16*   w_in_t  = (u16*)alloc((size_t)NL_ * H_ * MIDW * 2);
    u16*   w_out_t = (u16*)alloc((size_t)NL_ * CMB * H_ * 2);

    k_embed<<<NTOK, 256, 0, stream>>>(tokens, embed, x);
    k_tables<<<(NTOK + 255) / 256, 256, 0, stream>>>(ages, st, ct);
    k_transpose_bf16<<<dim3(MIDW / 64, H_ / 64, NL_), 256, 0, stream>>>(w_in, w_in_t, H_, MIDW);
    k_transpose_bf16<<<dim3(H_ / 64, CMB / 64, NL_), 256, 0, stream>>>(w_out, w_out_t, CMB, H_);

    for (int l = 0; l < NL_; l++) {
        k_ln<0><<<NTOK / 4, 256, 0, stream>>>(x, ln_scale + l * H_, ln_off + l * H_, xn_f, xn_h, nullptr);
        k_gemm<1, 128><<<dim3(NTOK / 128, MIDW / 128), 256, 0, stream>>>(
            xn_h, nullptr, w_in_t + (size_t)l * H_ * MIDW, b_in + (size_t)l * MIDW,
            nullptr, mid, nullptr, H_);
        k_rope_v<<<dim3(NTOK / 64, NH_), 256, 0, stream>>>(mid, st, ct, Vt);
        k_attn<<<NH_ * NB * 16, 128, 0, stream>>>(mid, Vt, attn);
        k_gemm<2, 64><<<dim3(NTOK / 128, H_ / 64), 256, 0, stream>>>(
            attn, mid, w_out_t + (size_t)l * CMB * H_, b_out + (size_t)l * H_,
            xn_f, nullptr, x, CMB);
    }
    k_ln<1><<<NTOK / 4, 256, 0, stream>>>(x, fscale, foff, nullptr, nullptr, out);
}

// Round 3
// 2076.831 us; speedup vs baseline: 1.2013x; 1.2013x over previous
//
#include <hip/hip_runtime.h>
#include <hip/hip_bf16.h>

#define H_    768
#define NH_   12
#define HD_   64
#define INTER_ 3072
#define NL_   6
#define NTOK  8192
#define SEG   512
#define NB    16
#define AW_   256
#define MIDW  5376   // 3H + INTER
#define CMB   3840   // H + INTER

typedef unsigned short u16;
typedef __bf16 bf16;
typedef bf16  bf16x8 __attribute__((ext_vector_type(8)));
typedef float f32x4  __attribute__((ext_vector_type(4)));
typedef u16   u16x8  __attribute__((ext_vector_type(8)));

#define GLOAD16(gp, lp) \
    __builtin_amdgcn_global_load_lds((const __attribute__((address_space(1))) void*)(gp), \
                                     (__attribute__((address_space(3))) void*)(lp), 16, 0, 0)

__device__ __forceinline__ u16 f2bf(float f) {
    union { float f; unsigned u; } v; v.f = f;
    unsigned u = v.u;
    u += 0x7fffu + ((u >> 16) & 1u);
    return (u16)(u >> 16);
}
__device__ __forceinline__ float bf2f(u16 h) {
    union { unsigned u; float f; } v; v.u = ((unsigned)h) << 16; return v.f;
}
__device__ __forceinline__ float gelu_f(float x) {
    float x3 = x * x * x;
    return 0.5f * x * (1.f + tanhf(0.7978845608028654f * (x + 0.044715f * x3)));
}

// ---------------- embed gather ----------------
__global__ void k_embed(const int* __restrict__ tokens, const float* __restrict__ embed,
                        float* __restrict__ x) {
    int row = blockIdx.x;
    int tok = tokens[row];
    const float* src = embed + (size_t)tok * H_;
    float* dst = x + (size_t)row * H_;
    for (int c = threadIdx.x; c < H_; c += blockDim.x) dst[c] = src[c];
}

// ---------------- rope tables (mimic jax fp32 path) ----------------
__global__ void k_tables(const float* __restrict__ ages, float* __restrict__ st,
                         float* __restrict__ ct) {
    int n = blockIdx.x * blockDim.x + threadIdx.x;
    if (n >= NTOK) return;
    float age = ages[n];
    for (int j = 0; j < 32; j++) {
        float e = (float)j * (2.0f / 31.0f);
        float invf = 1.0f / powf(10000.0f, e);
        float t = age * invf;
        st[n * 32 + j] = sinf(t);
        ct[n * 32 + j] = cosf(t);
    }
}

// ---------------- fp32 -> bf16 transpose (weights) ----------------
// src: [z][R][C] f32  ->  dst: [z][C][R] bf16
__global__ void k_transpose_bf16(const float* __restrict__ src, u16* __restrict__ dst,
                                 int R, int C) {
    __shared__ float T[64][65];
    int l = blockIdx.z;
    const float* s = src + (size_t)l * R * C;
    u16* d = dst + (size_t)l * R * C;
    int r0 = blockIdx.y * 64, c0 = blockIdx.x * 64;
    for (int i = threadIdx.x; i < 64 * 64; i += blockDim.x) {
        int r = i >> 6, c = i & 63;
        T[r][c] = s[(size_t)(r0 + r) * C + c0 + c];
    }
    __syncthreads();
    for (int i = threadIdx.x; i < 64 * 64; i += blockDim.x) {
        int rr = i >> 6, cc = i & 63;
        d[(size_t)(c0 + rr) * R + r0 + cc] = f2bf(T[cc][rr]);
    }
}

// ---------------- layernorm: wave per row ----------------
template<int FINAL>
__global__ __launch_bounds__(256) void k_ln(const float* __restrict__ x,
        const float* __restrict__ scale, const float* __restrict__ offset,
        float* __restrict__ xn_f, u16* __restrict__ xn_h, float* __restrict__ outf) {
    int wid = threadIdx.x >> 6, lane = threadIdx.x & 63;
    int row = blockIdx.x * 4 + wid;
    const float* xr = x + (size_t)row * H_;
    float4 v[3];
    float s = 0.f, sq = 0.f;
#pragma unroll
    for (int i = 0; i < 3; i++) {
        v[i] = *(const float4*)&xr[(i * 64 + lane) * 4];
        s  += v[i].x + v[i].y + v[i].z + v[i].w;
        sq += v[i].x * v[i].x + v[i].y * v[i].y + v[i].z * v[i].z + v[i].w * v[i].w;
    }
    for (int m = 1; m < 64; m <<= 1) { s += __shfl_xor(s, m); sq += __shfl_xor(sq, m); }
    float mean = s * (1.f / 768.f);
    float var  = sq * (1.f / 768.f) - mean * mean;
    float rstd = rsqrtf(fmaxf(var, 0.f) + 1e-5f);
#pragma unroll
    for (int i = 0; i < 3; i++) {
        int c0 = (i * 64 + lane) * 4;
        float4 sc = *(const float4*)&scale[c0];
        float4 of = *(const float4*)&offset[c0];
        float y0 = (v[i].x - mean) * rstd * sc.x + of.x;
        float y1 = (v[i].y - mean) * rstd * sc.y + of.y;
        float y2 = (v[i].z - mean) * rstd * sc.z + of.z;
        float y3 = (v[i].w - mean) * rstd * sc.w + of.w;
        if (FINAL) {
            *(float4*)&outf[(size_t)row * H_ + c0] = make_float4(y0, y1, y2, y3);
        } else {
            *(float4*)&xn_f[(size_t)row * H_ + c0] = make_float4(y0, y1, y2, y3);
            ushort4 h = make_ushort4(f2bf(y0), f2bf(y1), f2bf(y2), f2bf(y3));
            *(ushort4*)&xn_h[(size_t)row * H_ + c0] = h;
        }
    }
}

// ---------------- bf16 GEMM, 128xBN tile, BK=64, 4 waves ----------------
// global_load_lds staging with st-style XOR swizzle (rule #21: linear LDS dest,
// inverse-swizzled global SOURCE, swizzled ds_read). 16B slot t of LDS row r
// holds global[r][t ^ (r&7)] -> ds_read_b128 across 16 rows = 2-way banks (free).
// MODE 1 (BN=128): C(mid bf16) = A(xn_h [M][768]) * Bt(w_in_t)^T + b_in; gelu col>=2304
// MODE 2 (BN=64):  X(f32)      = [attn | mid_ff] * Bt(w_out_t)^T + b_out + xn_f
template<int MODE, int BN>
__global__ __launch_bounds__(256) void k_gemm(
        const u16* __restrict__ A, const u16* __restrict__ A2,
        const u16* __restrict__ Bt, const float* __restrict__ bias,
        const float* __restrict__ xn_f, u16* __restrict__ Cmid,
        float* __restrict__ Xout, int Ksz) {
    __shared__ __align__(16) u16 As[128 * 64];
    __shared__ __align__(16) u16 Bs[BN * 64];
    int m0 = blockIdx.x * 128;
    int n0 = blockIdx.y * BN;
    int tid = threadIdx.x;
    int wid = tid >> 6, lane = tid & 63;
    constexpr int MI = (BN == 128) ? 4 : 2;   // per-wave 16-row fragments
    constexpr int NI = 4;                      // per-wave 16-col fragments (64 cols)
    int wm = (BN == 128) ? (wid >> 1) : wid;
    int wn = (BN == 128) ? (wid & 1) : 0;
    f32x4 acc[MI][NI] = {};

    int r = tid >> 3;                                  // staging row within 32-row chunk
    int cs = ((tid & 7) ^ ((tid >> 3) & 7)) * 8;       // swizzled source col (u16)
    int wbase = (tid & 192) * 8;                       // wave-uniform LDS base: wid*512 u16

    int lm = lane & 15, lq = lane >> 4, l7 = lane & 7; // read-side indices

    int nkt = Ksz / 64;
    for (int kt = 0; kt < nkt; kt++) {
        int k0 = kt * 64;
        const u16* Ap; int lda, acol;
        if (MODE == 2 && k0 >= H_) { Ap = A2; lda = MIDW; acol = 2304 + (k0 - H_); }
        else                       { Ap = A;  lda = H_;   acol = k0; }
#pragma unroll
        for (int i = 0; i < 4; i++)
            GLOAD16(&Ap[(size_t)(m0 + i * 32 + r) * lda + acol + cs], &As[i * 2048 + wbase]);
#pragma unroll
        for (int i = 0; i < BN / 32; i++)
            GLOAD16(&Bt[(size_t)(n0 + i * 32 + r) * Ksz + k0 + cs], &Bs[i * 2048 + wbase]);
        __syncthreads();
#pragma unroll
        for (int kk = 0; kk < 64; kk += 32) {
            int slot = (((kk >> 3) + lq) ^ l7) * 8;    // swizzled read col (u16)
            bf16x8 af[MI], bfr[NI];
#pragma unroll
            for (int mi = 0; mi < MI; mi++)
                af[mi] = *(const bf16x8*)&As[(wm * (MI * 16) + mi * 16 + lm) * 64 + slot];
#pragma unroll
            for (int ni = 0; ni < NI; ni++)
                bfr[ni] = *(const bf16x8*)&Bs[(wn * 64 + ni * 16 + lm) * 64 + slot];
#pragma unroll
            for (int mi = 0; mi < MI; mi++)
#pragma unroll
                for (int ni = 0; ni < NI; ni++)
                    acc[mi][ni] = __builtin_amdgcn_mfma_f32_16x16x32_bf16(af[mi], bfr[ni], acc[mi][ni], 0, 0, 0);
        }
        __syncthreads();
    }
    // epilogue: D layout col=lane&15, row=(lane>>4)*4+reg
    int rbase = m0 + wm * (MI * 16), cbase = n0 + wn * 64;
#pragma unroll
    for (int mi = 0; mi < MI; mi++) {
#pragma unroll
        for (int ni = 0; ni < NI; ni++) {
            int col = cbase + ni * 16 + lm;
            float b = bias[col];
#pragma unroll
            for (int rr = 0; rr < 4; rr++) {
                int row = rbase + mi * 16 + lq * 4 + rr;
                float vv = acc[mi][ni][rr] + b;
                if (MODE == 1) {
                    if (col >= 2304) vv = gelu_f(vv);
                    Cmid[(size_t)row * MIDW + col] = f2bf(vv);
                } else {
                    Xout[(size_t)row * H_ + col] = vv + xn_f[(size_t)row * H_ + col];
                }
            }
        }
    }
}

// ---------------- rope on q,k (in place) + V transpose ----------------
__global__ __launch_bounds__(256) void k_rope_v(u16* __restrict__ mid,
        const float* __restrict__ st, const float* __restrict__ ct, u16* __restrict__ Vt) {
    int nb = blockIdx.x, h = blockIdx.y;
    int n0 = nb * 64;
    __shared__ u16 Vl[64][72];
    int tid = threadIdx.x;
    for (int i = tid; i < 64 * 32; i += 256) {
        int r = i >> 5, j = i & 31;
        int n = n0 + r;
        float s = st[n * 32 + j], c = ct[n * 32 + j];
        size_t base = (size_t)n * MIDW + h * 64 + 2 * j;
        float q0 = bf2f(mid[base]), q1 = bf2f(mid[base + 1]);
        mid[base]     = f2bf(q0 * c - q1 * s);
        mid[base + 1] = f2bf(q1 * c + q0 * s);
        float k0 = bf2f(mid[base + H_]), k1 = bf2f(mid[base + H_ + 1]);
        mid[base + H_]     = f2bf(k0 * c - k1 * s);
        mid[base + H_ + 1] = f2bf(k1 * c + k0 * s);
    }
    for (int i = tid; i < 64 * 64; i += 256) {
        int r = i >> 6, d = i & 63;
        Vl[r][d] = mid[(size_t)(n0 + r) * MIDW + 1536 + h * 64 + d];
    }
    __syncthreads();
    for (int i = tid; i < 64 * 64; i += 256) {
        int d = i >> 6, r = i & 63;
        Vt[(size_t)(h * 64 + d) * NTOK + n0 + r] = Vl[r][d];
    }
}

// ---------------- local windowed attention ----------------
// block: 128 threads (2 waves), 32 q-rows; grid: NH * NB * 16
__global__ __launch_bounds__(128) void k_attn(const u16* __restrict__ mid,
        const u16* __restrict__ Vt, u16* __restrict__ attn_out) {
    int bx = blockIdx.x;
    int h = bx >> 8, rem = bx & 255, b = rem >> 4, qq = rem & 15;
    int t0 = (qq * 32 - 255) >> 6; if (t0 < 0) t0 = 0;
    int tend = qq >> 1;
    int nt = tend - t0 + 1;          // <= 5
    int tid = threadIdx.x, wid = tid >> 6, lane = tid & 63;
    __shared__ float S[32][324];
    __shared__ float rl[32];
    int qrow0 = b * SEG + qq * 32;

    // Q fragments (rope already applied): wave's 16 rows
    bf16x8 qf[2];
    {
        int r = qrow0 + wid * 16 + (lane & 15);
        const u16* qp = &mid[(size_t)r * MIDW + h * 64];
        qf[0] = *(const bf16x8*)&qp[(lane >> 4) * 8];
        qf[1] = *(const bf16x8*)&qp[32 + (lane >> 4) * 8];
    }
    // S = Q K^T (scaled, masked)
    for (int t = 0; t < nt; t++) {
        int j0 = (t0 + t) * 64;
        f32x4 sa[4] = {};
#pragma unroll
        for (int kf = 0; kf < 2; kf++) {
            bf16x8 kfr[4];
#pragma unroll
            for (int nf = 0; nf < 4; nf++) {
                int key = b * SEG + j0 + nf * 16 + (lane & 15);
                kfr[nf] = *(const bf16x8*)&mid[(size_t)key * MIDW + H_ + h * 64 + kf * 32 + (lane >> 4) * 8];
            }
#pragma unroll
            for (int nf = 0; nf < 4; nf++)
                sa[nf] = __builtin_amdgcn_mfma_f32_16x16x32_bf16(qf[kf], kfr[nf], sa[nf], 0, 0, 0);
        }
#pragma unroll
        for (int nf = 0; nf < 4; nf++) {
            int j = j0 + nf * 16 + (lane & 15);
#pragma unroll
            for (int r = 0; r < 4; r++) {
                int row = wid * 16 + (lane >> 4) * 4 + r;
                int qi = qq * 32 + row;
                bool valid = (j <= qi) && (qi - j < AW_);
                S[row][t * 64 + nf * 16 + (lane & 15)] = valid ? sa[nf][r] * 0.125f : -1e30f;
            }
        }
    }
    __syncthreads();
    // softmax: 4 threads per row
    {
        int row = tid >> 2, sub = tid & 3;
        int ncol = nt * 64;
        float m = -1e30f;
        for (int c = sub; c < ncol; c += 4) m = fmaxf(m, S[row][c]);
        m = fmaxf(m, __shfl_xor(m, 1)); m = fmaxf(m, __shfl_xor(m, 2));
        float l = 0.f;
        for (int c = sub; c < ncol; c += 4) { float p = __expf(S[row][c] - m); S[row][c] = p; l += p; }
        l += __shfl_xor(l, 1); l += __shfl_xor(l, 2);
        if (sub == 0) rl[row] = 1.f / l;
    }
    __syncthreads();
    // O = P V
    f32x4 oacc[4] = {};
    for (int t = 0; t < nt; t++) {
#pragma unroll
        for (int kf = 0; kf < 2; kf++) {
            const float* sp = &S[wid * 16 + (lane & 15)][t * 64 + kf * 32 + (lane >> 4) * 8];
            float4 f1 = *(const float4*)sp;
            float4 f2 = *(const float4*)(sp + 4);
            u16x8 pt;
            pt[0] = f2bf(f1.x); pt[1] = f2bf(f1.y); pt[2] = f2bf(f1.z); pt[3] = f2bf(f1.w);
            pt[4] = f2bf(f2.x); pt[5] = f2bf(f2.y); pt[6] = f2bf(f2.z); pt[7] = f2bf(f2.w);
            bf16x8 pa = __builtin_bit_cast(bf16x8, pt);
#pragma unroll
            for (int nf = 0; nf < 4; nf++) {
                int d = h * 64 + nf * 16 + (lane & 15);
                const u16* vp = &Vt[(size_t)d * NTOK + b * SEG + (t0 + t) * 64 + kf * 32 + (lane >> 4) * 8];
                bf16x8 vb = *(const bf16x8*)vp;
                oacc[nf] = __builtin_amdgcn_mfma_f32_16x16x32_bf16(pa, vb, oacc[nf], 0, 0, 0);
            }
        }
    }
#pragma unroll
    for (int nf = 0; nf < 4; nf++) {
#pragma unroll
        for (int r = 0; r < 4; r++) {
            int row = wid * 16 + (lane >> 4) * 4 + r;
            float sc = rl[row];
            int grow = qrow0 + row;
            attn_out[(size_t)grow * H_ + h * 64 + nf * 16 + (lane & 15)] = f2bf(oacc[nf][r] * sc);
        }
    }
}

extern "C" void kernel_launch(void* const* d_in, const int* in_sizes, int n_in,
                              void* d_out, int out_size, void* d_ws, size_t ws_size,
                              hipStream_t stream) {
    const int*   tokens   = (const int*)d_in[0];
    const float* ages     = (const float*)d_in[1];
    const float* embed    = (const float*)d_in[4];
    const float* ln_scale = (const float*)d_in[5];
    const float* ln_off   = (const float*)d_in[6];
    const float* w_in     = (const float*)d_in[7];
    const float* b_in     = (const float*)d_in[8];
    const float* w_out    = (const float*)d_in[9];
    const float* b_out    = (const float*)d_in[10];
    const float* fscale   = (const float*)d_in[11];
    const float* foff     = (const float*)d_in[12];
    float* out = (float*)d_out;

    char* ws = (char*)d_ws;
    size_t off = 0;
    auto alloc = [&](size_t bytes) { void* p = ws + off; off += (bytes + 255) & ~(size_t)255; return p; };
    float* st      = (float*)alloc((size_t)NTOK * 32 * 4);
    float* ct      = (float*)alloc((size_t)NTOK * 32 * 4);
    float* x       = (float*)alloc((size_t)NTOK * H_ * 4);
    float* xn_f    = (float*)alloc((size_t)NTOK * H_ * 4);
    u16*   xn_h    = (u16*)alloc((size_t)NTOK * H_ * 2);
    u16*   mid     = (u16*)alloc((size_t)NTOK * MIDW * 2);
    u16*   Vt      = (u16*)alloc((size_t)H_ * NTOK * 2);
    u16*   attn    = (u16*)alloc((size_t)NTOK * H_ * 2);
    u16*   w_in_t  = (u16*)alloc((size_t)NL_ * H_ * MIDW * 2);
    u16*   w_out_t = (u16*)alloc((size_t)NL_ * CMB * H_ * 2);

    k_embed<<<NTOK, 256, 0, stream>>>(tokens, embed, x);
    k_tables<<<(NTOK + 255) / 256, 256, 0, stream>>>(ages, st, ct);
    k_transpose_bf16<<<dim3(MIDW / 64, H_ / 64, NL_), 256, 0, stream>>>(w_in, w_in_t, H_, MIDW);
    k_transpose_bf16<<<dim3(H_ / 64, CMB / 64, NL_), 256, 0, stream>>>(w_out, w_out_t, CMB, H_);

    for (int l = 0; l < NL_; l++) {
        k_ln<0><<<NTOK / 4, 256, 0, stream>>>(x, ln_scale + l * H_, ln_off + l * H_, xn_f, xn_h, nullptr);
        k_gemm<1, 128><<<dim3(NTOK / 128, MIDW / 128), 256, 0, stream>>>(
            xn_h, nullptr, w_in_t + (size_t)l * H_ * MIDW, b_in + (size_t)l * MIDW,
            nullptr, mid, nullptr, H_);
        k_rope_v<<<dim3(NTOK / 64, NH_), 256, 0, stream>>>(mid, st, ct, Vt);
        k_attn<<<NH_ * NB * 16, 128, 0, stream>>>(mid, Vt, attn);
        k_gemm<2, 64><<<dim3(NTOK / 128, H_ / 64), 256, 0, stream>>>(
            attn, mid, w_out_t + (size_t)l * CMB * H_, b_out + (size_t)l * H_,
            xn_f, nullptr, x, CMB);
    }
    k_ln<1><<<NTOK / 4, 256, 0, stream>>>(x, fscale, foff, nullptr, nullptr, out);
}